// Round 13
// baseline (231.508 us; speedup 1.0000x reference)
//
#include <hip/hip_runtime.h>
#include <cstdint>
#include <cstddef>

#define EMB  1024
#define DM   64
#define NH   16
#define SLEN 2048
#define BS   2

typedef _Float16 f16x8 __attribute__((ext_vector_type(8)));
typedef _Float16 f16x4 __attribute__((ext_vector_type(4)));
typedef __fp16   hf2   __attribute__((ext_vector_type(2)));
typedef __fp16   hf4   __attribute__((ext_vector_type(4)));
typedef __fp16   hf8   __attribute__((ext_vector_type(8)));
typedef float    f32x4 __attribute__((ext_vector_type(4)));

#define ASYNC_LD16(gp, lp)                                                        \
    __builtin_amdgcn_global_load_lds(                                             \
        (const __attribute__((address_space(1))) void*)(gp),                      \
        (__attribute__((address_space(3))) void*)(lp), 16, 0, 0)

// ---------------------------------------------------------------------------
// prep (weights only now): transpose W[K][N] fp32 -> W^T[N][K] fp16.
// The Q/K/V fp32->fp16 convert is fused into gemm_qkv's A-staging (saves a
// full 48MB-read + 24MB-write pass and 6/7 of this grid).
// ---------------------------------------------------------------------------
__global__ __launch_bounds__(256)
void prep(const float* __restrict__ Wq, const float* __restrict__ Wk,
          const float* __restrict__ Wv, const float* __restrict__ Wo,
          _Float16* __restrict__ WqT, _Float16* __restrict__ WkT,
          _Float16* __restrict__ WvT, _Float16* __restrict__ WoT)
{
    __shared__ float t[64][65];
    const float* W;
    _Float16*    T;
    switch (blockIdx.z) {
        case 0:  W = Wq; T = WqT; break;
        case 1:  W = Wk; T = WkT; break;
        case 2:  W = Wv; T = WvT; break;
        default: W = Wo; T = WoT; break;
    }
    const int tid = threadIdx.x;
    const int bn  = (blockIdx.x & 15) * 64;
    const int bk  = (blockIdx.x >> 4) * 64;

    #pragma unroll
    for (int p = 0; p < 4; ++p) {
        int row = p * 16 + (tid >> 4);
        int col = (tid & 15) * 4;
        float4 v = *(const float4*)(W + (size_t)(bk + row) * EMB + bn + col);
        t[row][col+0] = v.x; t[row][col+1] = v.y; t[row][col+2] = v.z; t[row][col+3] = v.w;
    }
    __syncthreads();
    #pragma unroll
    for (int p = 0; p < 4; ++p) {
        int nr = p * 16 + (tid >> 4);
        int kc = (tid & 15) * 4;
        f16x4 o;
        o[0] = (_Float16)t[kc+0][nr];
        o[1] = (_Float16)t[kc+1][nr];
        o[2] = (_Float16)t[kc+2][nr];
        o[3] = (_Float16)t[kc+3][nr];
        *(f16x4*)&T[(size_t)(bn + nr) * EMB + bk + kc] = o;
    }
}

// ---------------------------------------------------------------------------
// MFMA GEMM core v5: R6-verified v3 structure (BM=64 x BN=128 x BK=64,
// 4 waves 2Mx2N, XOR-chunk swizzled LDS, single-barrier dbuf pipeline),
// templated on the A-operand source:
//   A32=false: A is fp16, staged via global_load_lds (gemm_out path).
//   A32=true : A is fp32 (raw Q/K/V), reg-staged: load 4x float4 for tile
//     t+1 at loop top (issued BEFORE B's glds so the compiler's auto-vmcnt
//     for the cvt leaves B in flight), convert with RTN casts after the
//     MFMAs, ds_write_b128 into the swizzled As slot of the other buffer.
//     Safe: that buffer's readers finished behind the previous barrier, and
//     __syncthreads' lgkm drain orders the writes before the next reads.
// C = scale*(A @ Bt^T + bias)
// ---------------------------------------------------------------------------
template <bool A32>
__device__ __forceinline__
void gemm_core(const void* __restrict__ Aptr, const _Float16* __restrict__ Bt,
               const float* __restrict__ bias, float* __restrict__ Cf,
               _Float16* __restrict__ Ch, int M, int N, int K,
               float scale, int mode, int bx, int by)
{
    __shared__ __align__(16) _Float16 As[2][64 * 64];    // 16 KB
    __shared__ __align__(16) _Float16 Bs[2][128 * 64];   // 32 KB

    const int tid  = threadIdx.x;
    const int lane = tid & 63;
    const int wave = tid >> 6;          // 0..3
    const int c    = lane & 15;
    const int quad = lane >> 4;
    const int bm   = by * 64;
    const int bn   = bx * 128;
    const int wm   = (wave >> 1) * 32;  // 2 waves in M
    const int wn   = (wave & 1) * 64;   // 2 waves in N

    f32x4 acc[2][4];
    #pragma unroll
    for (int i = 0; i < 2; ++i)
        #pragma unroll
        for (int j = 0; j < 4; ++j)
            #pragma unroll
            for (int r = 0; r < 4; ++r) acc[i][j][r] = 0.f;

    const size_t Kb = (size_t)K * 2;                     // fp16 row stride bytes
    const int    lc = ((tid & 7) ^ ((tid >> 3) & 7)) * 16;
    const char* gB = (const char*)Bt + (size_t)(bn + (tid >> 3)) * Kb + lc;

    const char*  gA16 = nullptr;
    const float* gA32 = nullptr;
    int aswz0 = 0, aswz1 = 0;
    if constexpr (A32) {
        const int ar  = tid >> 2;        // row 0..63
        const int acg = tid & 3;         // 16-col group
        gA32  = (const float*)Aptr + (size_t)(bm + ar) * K + acg * 16;
        aswz0 = ar * 64 + (((2*acg    ) ^ (ar & 7)) * 8);
        aswz1 = ar * 64 + (((2*acg + 1) ^ (ar & 7)) * 8);
    } else {
        gA16 = (const char*)Aptr + (size_t)(bm + (tid >> 3)) * Kb + lc;
    }

    const int NS = K / 64;

    auto stageB = [&](int buf, int t) {
        const size_t ko = (size_t)t * 128;               // 64 cols * 2 B
        char* lB = (char*)&Bs[buf][0] + wave * 1024;
        ASYNC_LD16(gB + ko,           lB);
        ASYNC_LD16(gB + 32*Kb + ko,   lB + 4096);
        ASYNC_LD16(gB + 64*Kb + ko,   lB + 8192);
        ASYNC_LD16(gB + 96*Kb + ko,   lB + 12288);
    };
    auto stageA16 = [&](int buf, int t) {
        const size_t ko = (size_t)t * 128;
        char* lA = (char*)&As[buf][0] + wave * 1024;
        ASYNC_LD16(gA16 + ko,         lA);
        ASYNC_LD16(gA16 + 32*Kb + ko, lA + 4096);
    };
    auto writeA32 = [&](int buf, const float4& a0, const float4& a1,
                        const float4& a2, const float4& a3) {
        f16x8 h0, h1;
        h0[0] = (_Float16)a0.x; h0[1] = (_Float16)a0.y;
        h0[2] = (_Float16)a0.z; h0[3] = (_Float16)a0.w;
        h0[4] = (_Float16)a1.x; h0[5] = (_Float16)a1.y;
        h0[6] = (_Float16)a1.z; h0[7] = (_Float16)a1.w;
        h1[0] = (_Float16)a2.x; h1[1] = (_Float16)a2.y;
        h1[2] = (_Float16)a2.z; h1[3] = (_Float16)a2.w;
        h1[4] = (_Float16)a3.x; h1[5] = (_Float16)a3.y;
        h1[6] = (_Float16)a3.z; h1[7] = (_Float16)a3.w;
        *(f16x8*)&As[buf][aswz0] = h0;
        *(f16x8*)&As[buf][aswz1] = h1;
    };

    // prologue: tile 0
    if constexpr (A32) {
        float4 a0 = *(const float4*)(gA32 + 0);
        float4 a1 = *(const float4*)(gA32 + 4);
        float4 a2 = *(const float4*)(gA32 + 8);
        float4 a3 = *(const float4*)(gA32 + 12);
        stageB(0, 0);
        writeA32(0, a0, a1, a2, a3);
    } else {
        stageA16(0, 0);
        stageB(0, 0);
    }
    __syncthreads();

    int cur = 0;
    for (int t = 0; t < NS; ++t) {
        float4 a0, a1, a2, a3;
        if constexpr (A32) {
            if (t + 1 < NS) {               // issue A loads first
                const float* p = gA32 + (size_t)(t + 1) * 64;
                a0 = *(const float4*)(p + 0);
                a1 = *(const float4*)(p + 4);
                a2 = *(const float4*)(p + 8);
                a3 = *(const float4*)(p + 12);
            }
        }
        if (t + 1 < NS) {
            if constexpr (!A32) stageA16(cur ^ 1, t + 1);
            stageB(cur ^ 1, t + 1);         // B glds fly during compute
        }

        #pragma unroll
        for (int kk = 0; kk < 2; ++kk) {
            f16x8 af[2], bf[4];
            #pragma unroll
            for (int i = 0; i < 2; ++i)
                af[i] = *(const f16x8*)
                    &As[cur][(wm + i*16 + c) * 64 + (((kk*4 + quad) ^ (c & 7)) * 8)];
            #pragma unroll
            for (int j = 0; j < 4; ++j)
                bf[j] = *(const f16x8*)
                    &Bs[cur][(wn + j*16 + c) * 64 + (((kk*4 + quad) ^ (c & 7)) * 8)];
            #pragma unroll
            for (int i = 0; i < 2; ++i)
                #pragma unroll
                for (int j = 0; j < 4; ++j)
                    acc[i][j] = __builtin_amdgcn_mfma_f32_16x16x32_f16(af[i], bf[j], acc[i][j], 0, 0, 0);
        }

        if constexpr (A32) {
            if (t + 1 < NS) writeA32(cur ^ 1, a0, a1, a2, a3);
        }
        __syncthreads();               // drains glds + lgkm: next buf ready
        cur ^= 1;
    }

    float bcol[4];
    #pragma unroll
    for (int j = 0; j < 4; ++j) bcol[j] = bias[bn + wn + j * 16 + c];

    #pragma unroll
    for (int i = 0; i < 2; ++i) {
        int m0 = bm + wm + i * 16 + quad * 4;
        #pragma unroll
        for (int j = 0; j < 4; ++j) {
            int n = bn + wn + j * 16 + c;
            if (mode == 0) {
                #pragma unroll
                for (int r = 0; r < 4; ++r)
                    Cf[(size_t)(m0 + r) * N + n] = acc[i][j][r] + bcol[j];
            } else if (mode == 1) {
                int h = n >> 6, d = n & 63;
                #pragma unroll
                for (int r = 0; r < 4; ++r) {
                    int mm = m0 + r;
                    int b = mm >> 11, l = mm & (SLEN - 1);
                    Ch[(((size_t)(b * NH + h)) * SLEN + l) * DM + d] =
                        (_Float16)((acc[i][j][r] + bcol[j]) * scale);
                }
            } else {
                int h = n >> 6, d = n & 63;
                int b = m0 >> 11, l = m0 & (SLEN - 1);
                f16x4 o;
                #pragma unroll
                for (int r = 0; r < 4; ++r)
                    o[r] = (_Float16)(acc[i][j][r] + bcol[j]);
                *(f16x4*)&Ch[(((size_t)(b * NH + h)) * DM + d) * SLEN + l] = o;
            }
        }
    }
}

// XCD-bijective block swizzle: all 8 N-blocks sharing an A-panel (same by)
// get the same wid%8 -> same XCD L2 -> A fetched once per XCD, not 8x.
__device__ __forceinline__ void xcd_swz(int& bx, int& by)
{
    int wid = blockIdx.x + 8 * blockIdx.y;   // 0..511, = flat wg id per z
    bx = wid >> 6;                           // 0..7
    by = wid & 63;                           // 0..63
}

__global__ __launch_bounds__(256)
void gemm_qkv(const float* __restrict__ Q, const float* __restrict__ K,
              const float* __restrict__ V,
              const _Float16* __restrict__ WqT, const _Float16* __restrict__ WkT,
              const _Float16* __restrict__ WvT,
              const float* __restrict__ bq, const float* __restrict__ bk,
              const float* __restrict__ bv,
              _Float16* __restrict__ q_ws, _Float16* __restrict__ k_ws,
              _Float16* __restrict__ v_ws)
{
    const float* A;
    const _Float16* Bt;
    const float* bias;
    _Float16* Ch;
    float scale;
    int mode;
    // q-scale folds 1/sqrt(DM) AND log2(e) so attention can use exp2 directly.
    if (blockIdx.z == 0)      { A = Q; Bt = WqT; bias = bq; Ch = q_ws; scale = 0.18033688f; mode = 1; }
    else if (blockIdx.z == 1) { A = K; Bt = WkT; bias = bk; Ch = k_ws; scale = 1.0f;        mode = 1; }
    else                      { A = V; Bt = WvT; bias = bv; Ch = v_ws; scale = 1.0f;        mode = 2; }
    int bx, by; xcd_swz(bx, by);
    gemm_core<true>(A, Bt, bias, nullptr, Ch, BS * SLEN, NH * DM, EMB, scale, mode, bx, by);
}

__global__ __launch_bounds__(256)
void gemm_out(const _Float16* __restrict__ Oh, const _Float16* __restrict__ WoT,
              const float* __restrict__ bo, float* __restrict__ out)
{
    int bx, by; xcd_swz(bx, by);
    gemm_core<false>(Oh, WoT, bo, out, nullptr, BS * SLEN, EMB, NH * DM, 1.0f, 0, bx, by);
}

// ---------------------------------------------------------------------------
// MFMA flash attention v10 (R8-verified, 47.5us / 34% occ): 8 waves =
// 4 q-groups (32 rows) x 2 key-halves (32 keys); all-K=32 MFMA; no-max
// exp2 softmax; XOR-chunk-swizzled LDS; 4-deep LDS ring with counted-vmcnt
// boundaries (prefetch 3 ahead, s_waitcnt vmcnt(4) + raw s_barrier).
// R9/R12's 64-row-per-wave variant halved LDS reads (conflicts 4.19M->2.10M
// confirmed) but lost TLP (occ 34->17%) and netted 50.6us -> reverted.
// qw/kw: [b][h][l][d] fp16;  vwT: [b][h][d][l] fp16;  ow: [b][l][h*64+d] fp16
// ---------------------------------------------------------------------------
__global__ __launch_bounds__(512)
void attn_mfma(const _Float16* __restrict__ qw, const _Float16* __restrict__ kw,
               const _Float16* __restrict__ vwT, _Float16* __restrict__ ow)
{
    // swizzled: element (row, col) at row*64 + ((col/8 ^ (row&7))*8 + col%8)
    __shared__ __align__(16) _Float16 Kt[4][64 * 64];   // [key][d], 32 KB ring
    __shared__ __align__(16) _Float16 Vt[4][64 * 64];   // [d][key], 32 KB ring

    const int tid  = threadIdx.x;
    const int lane = tid & 63;
    const int wave = tid >> 6;          // 0..7
    const int c    = lane & 15;
    const int quad = lane >> 4;
    const int qg   = wave & 3;          // q-group: 32 rows
    const int kh   = wave >> 2;         // key-half: 32 keys
    const int bh   = blockIdx.y;
    const int b    = bh >> 4;
    const int h    = bh & 15;
    const int qbase = blockIdx.x * 128 + qg * 32;

    const _Float16* kb = kw  + (size_t)bh * SLEN * DM;
    const _Float16* vb = vwT + (size_t)bh * DM * SLEN;
    const _Float16* qb = qw  + (size_t)bh * SLEN * DM;

    // Q fragments (B-operand of S^T = K Q^T): lane: qrow = t*16+c, d = ch*32+quad*8+j
    f16x8 qf[2][2];
    #pragma unroll
    for (int t = 0; t < 2; ++t)
        #pragma unroll
        for (int ch = 0; ch < 2; ++ch)
            qf[t][ch] = *(const f16x8*)(qb + (size_t)(qbase + t*16 + c) * DM + ch*32 + quad*8);

    f32x4 oacc[2][4];
    f32x4 lacc[2];
    #pragma unroll
    for (int t = 0; t < 2; ++t) {
        #pragma unroll
        for (int dg = 0; dg < 4; ++dg)
            #pragma unroll
            for (int r = 0; r < 4; ++r) oacc[t][dg][r] = 0.f;
        #pragma unroll
        for (int r = 0; r < 4; ++r) lacc[t][r] = 0.f;
    }

    const f16x8 ones8 = {(_Float16)1.f, (_Float16)1.f, (_Float16)1.f, (_Float16)1.f,
                         (_Float16)1.f, (_Float16)1.f, (_Float16)1.f, (_Float16)1.f};
    const f32x4 zero4 = {0.f, 0.f, 0.f, 0.f};

    // --- global_load_lds staging (per wave: 1 K-load + 1 V-load per tile;
    // lane's 16 B at dest row w*8 + lane/8, phys chunk lane&7; source holds
    // the swizzled chunk (lane&7) ^ (row&7), row&7 = (lane>>3)&7).
    const int r0  = wave * 8 + (lane >> 3);
    const int lc0 = (((lane & 7) ^ ((lane >> 3) & 7)) * 16);
    const char* gk = (const char*)kb + r0 * 128 + lc0;             // K row stride 128 B
    const char* gv = (const char*)vb + (size_t)r0 * 4096 + lc0;    // V^T row stride 4096 B

    auto stage = [&](int buf) {
        char* pk = (char*)&Kt[buf][0] + wave * 1024;
        char* pv = (char*)&Vt[buf][0] + wave * 1024;
        ASYNC_LD16(gk, pk);
        ASYNC_LD16(gv, pv);
        gk += 8192;   // 64 keys * 128 B
        gv += 128;    // 64 keys * 2 B per d-row
    };

    // prologue: fill ring slots 0,1,2 (6 loads/wave outstanding)
    stage(0); stage(1); stage(2);
    asm volatile("s_waitcnt vmcnt(4)" ::: "memory");   // slot 0 landed
    __builtin_amdgcn_s_barrier();
    asm volatile("" ::: "memory");

    const int NT = SLEN / 64;
    for (int t = 0; t < NT; ++t) {
        stage((t + 3) & 3);      // 3 tiles ahead (tail over-reads stay in ws)
        const int cb = t & 3;

        // K fragments (A-operand) for this wave's key-half:
        // key = kh*32 + kg*16 + c, logical chunk ch*4+quad (row&7 = c&7)
        f16x8 kf[2][2];
        #pragma unroll
        for (int kg = 0; kg < 2; ++kg)
            #pragma unroll
            for (int ch = 0; ch < 2; ++ch)
                kf[kg][ch] = *(const f16x8*)
                    &Kt[cb][(kh*32 + kg*16 + c) * 64 + (((ch*4 + quad) ^ (c & 7)) * 8)];

        // S^T = K Q^T : lane: key = kh*32 + kg*16 + quad*4 + r, qrow = t2*16+c
        f32x4 s[2][2];
        #pragma unroll
        for (int t2 = 0; t2 < 2; ++t2)
            #pragma unroll
            for (int kg = 0; kg < 2; ++kg) {
                s[t2][kg] = __builtin_amdgcn_mfma_f32_16x16x32_f16(kf[kg][0], qf[t2][0], zero4,     0, 0, 0);
                s[t2][kg] = __builtin_amdgcn_mfma_f32_16x16x32_f16(kf[kg][1], qf[t2][1], s[t2][kg], 0, 0, 0);
            }

        // p = 2^(s') packed into the K=32 A-fragment order: pf8[t2] element j
        // holds key (rel. to kh*32) = (j>=4)*16 + quad*4 + (j&3)
        f16x8 pf8[2];
        #pragma unroll
        for (int t2 = 0; t2 < 2; ++t2) {
            hf4 h4[2];
            #pragma unroll
            for (int u = 0; u < 2; ++u) {
                float p0 = __builtin_amdgcn_exp2f(s[t2][u][0]);
                float p1 = __builtin_amdgcn_exp2f(s[t2][u][1]);
                float p2 = __builtin_amdgcn_exp2f(s[t2][u][2]);
                float p3 = __builtin_amdgcn_exp2f(s[t2][u][3]);
                hf2 lo = __builtin_amdgcn_cvt_pkrtz(p0, p1);
                hf2 hi = __builtin_amdgcn_cvt_pkrtz(p2, p3);
                h4[u] = __builtin_shufflevector(lo, hi, 0, 1, 2, 3);
            }
            hf8 h8 = __builtin_shufflevector(h4[0], h4[1], 0, 1, 2, 3, 4, 5, 6, 7);
            pf8[t2] = __builtin_bit_cast(f16x8, h8);
        }

        // l += P @ ones  (K=32; with B = ones any k-permutation is valid)
        #pragma unroll
        for (int t2 = 0; t2 < 2; ++t2)
            lacc[t2] = __builtin_amdgcn_mfma_f32_16x16x32_f16(pf8[t2], ones8, lacc[t2], 0, 0, 0);

        // O += P V  (K=32: B element j = V[kh*32 + key(quad,j)][d=dg*16+c])
        #pragma unroll
        for (int dg = 0; dg < 4; ++dg) {
            f16x4 vf[2];
            #pragma unroll
            for (int u = 0; u < 2; ++u)
                vf[u] = *(const f16x4*)
                    &Vt[cb][(dg*16 + c) * 64 +
                            (((kh*4 + 2*u + (quad >> 1)) ^ (c & 7)) * 8) + (quad & 1) * 4];
            f16x8 v8 = __builtin_shufflevector(vf[0], vf[1], 0, 1, 2, 3, 4, 5, 6, 7);
            #pragma unroll
            for (int t2 = 0; t2 < 2; ++t2)
                oacc[t2][dg] = __builtin_amdgcn_mfma_f32_16x16x32_f16(pf8[t2], v8, oacc[t2][dg], 0, 0, 0);
        }

        // tile boundary: counted wait (newest 2 tiles' loads stay in flight)
        asm volatile("s_waitcnt vmcnt(4)" ::: "memory");
        __builtin_amdgcn_s_barrier();
        asm volatile("" ::: "memory");
    }

    __syncthreads();   // drain all outstanding loads before LDS reuse

    // --- merge key-half partials (O, l) through LDS, two rounds over t.
    // Round size: 4 qg x 64 lanes x 20 f32 = 20 KB (fits in Kt's 32 KB).
    float* mb = (float*)&Kt[0][0];
    #pragma unroll
    for (int t = 0; t < 2; ++t) {
        if (kh == 1) {
            float* p = mb + ((qg * 64 + lane) * 20);
            *(f32x4*)(p +  0) = oacc[t][0];
            *(f32x4*)(p +  4) = oacc[t][1];
            *(f32x4*)(p +  8) = oacc[t][2];
            *(f32x4*)(p + 12) = oacc[t][3];
            *(f32x4*)(p + 16) = lacc[t];
        }
        __syncthreads();
        if (kh == 0) {
            const float* p = mb + ((qg * 64 + lane) * 20);
            f32x4 po[4], pl;
            po[0] = *(const f32x4*)(p +  0);
            po[1] = *(const f32x4*)(p +  4);
            po[2] = *(const f32x4*)(p +  8);
            po[3] = *(const f32x4*)(p + 12);
            pl    = *(const f32x4*)(p + 16);
            #pragma unroll
            for (int r = 0; r < 4; ++r) {
                float linv = 1.0f / (lacc[t][r] + pl[r]);
                int row = qbase + t*16 + quad*4 + r;
                #pragma unroll
                for (int dg = 0; dg < 4; ++dg)
                    ow[((size_t)b * SLEN + row) * EMB + h * DM + dg*16 + c] =
                        (_Float16)((oacc[t][dg][r] + po[dg][r]) * linv);
            }
        }
        __syncthreads();
    }
}

// ---------------------------------------------------------------------------
extern "C" void kernel_launch(void* const* d_in, const int* in_sizes, int n_in,
                              void* d_out, int out_size, void* d_ws, size_t ws_size,
                              hipStream_t stream)
{
    const float* Q  = (const float*)d_in[0];
    const float* K  = (const float*)d_in[1];
    const float* V  = (const float*)d_in[2];
    const float* Wq = (const float*)d_in[3];
    const float* bq = (const float*)d_in[4];
    const float* Wk = (const float*)d_in[5];
    const float* bk = (const float*)d_in[6];
    const float* Wv = (const float*)d_in[7];
    const float* bv = (const float*)d_in[8];
    const float* Wo = (const float*)d_in[9];
    const float* bo = (const float*)d_in[10];
    float* out = (float*)d_out;

    const size_t MN = (size_t)BS * SLEN * NH * DM;   // 4M halves
    const size_t WW = (size_t)EMB * NH * DM;         // 1M halves

    _Float16* base = (_Float16*)d_ws;
    _Float16* WqT  = base;
    _Float16* WkT  = WqT + WW;
    _Float16* WvT  = WkT + WW;
    _Float16* WoT  = WvT + WW;
    _Float16* q_ws = WoT + WW;
    _Float16* k_ws = q_ws + MN;
    _Float16* v_ws = k_ws + MN;
    _Float16* o_ws = v_ws + MN;

    dim3 blk(256);

    prep<<<dim3(256, 1, 4), blk, 0, stream>>>(Wq, Wk, Wv, Wo,
                                              WqT, WkT, WvT, WoT);

    gemm_qkv<<<dim3(8, 64, 3), blk, 0, stream>>>(Q, K, V, WqT, WkT, WvT,
                                                 bq, bk, bv, q_ws, k_ws, v_ws);

    attn_mfma<<<dim3(SLEN / 128, BS * NH), dim3(512), 0, stream>>>(q_ws, k_ws, v_ws, o_ws);

    gemm_out<<<dim3(8, 64, 1), blk, 0, stream>>>(o_ws, WoT, bo, out);
}

// Round 14
// 225.636 us; speedup vs baseline: 1.0260x; 1.0260x over previous
//
#include <hip/hip_runtime.h>
#include <cstdint>
#include <cstddef>

#define EMB  1024
#define DM   64
#define NH   16
#define SLEN 2048
#define BS   2

typedef _Float16 f16x8 __attribute__((ext_vector_type(8)));
typedef _Float16 f16x4 __attribute__((ext_vector_type(4)));
typedef __fp16   hf2   __attribute__((ext_vector_type(2)));
typedef __fp16   hf4   __attribute__((ext_vector_type(4)));
typedef __fp16   hf8   __attribute__((ext_vector_type(8)));
typedef float    f32x4 __attribute__((ext_vector_type(4)));

#define ASYNC_LD16(gp, lp)                                                        \
    __builtin_amdgcn_global_load_lds(                                             \
        (const __attribute__((address_space(1))) void*)(gp),                      \
        (__attribute__((address_space(3))) void*)(lp), 16, 0, 0)

// ---------------------------------------------------------------------------
// prep (weights only): transpose W[K][N] fp32 -> W^T[N][K] fp16.
// ---------------------------------------------------------------------------
__global__ __launch_bounds__(256)
void prep(const float* __restrict__ Wq, const float* __restrict__ Wk,
          const float* __restrict__ Wv, const float* __restrict__ Wo,
          _Float16* __restrict__ WqT, _Float16* __restrict__ WkT,
          _Float16* __restrict__ WvT, _Float16* __restrict__ WoT)
{
    __shared__ float t[64][65];
    const float* W;
    _Float16*    T;
    switch (blockIdx.z) {
        case 0:  W = Wq; T = WqT; break;
        case 1:  W = Wk; T = WkT; break;
        case 2:  W = Wv; T = WvT; break;
        default: W = Wo; T = WoT; break;
    }
    const int tid = threadIdx.x;
    const int bn  = (blockIdx.x & 15) * 64;
    const int bk  = (blockIdx.x >> 4) * 64;

    #pragma unroll
    for (int p = 0; p < 4; ++p) {
        int row = p * 16 + (tid >> 4);
        int col = (tid & 15) * 4;
        float4 v = *(const float4*)(W + (size_t)(bk + row) * EMB + bn + col);
        t[row][col+0] = v.x; t[row][col+1] = v.y; t[row][col+2] = v.z; t[row][col+3] = v.w;
    }
    __syncthreads();
    #pragma unroll
    for (int p = 0; p < 4; ++p) {
        int nr = p * 16 + (tid >> 4);
        int kc = (tid & 15) * 4;
        f16x4 o;
        o[0] = (_Float16)t[kc+0][nr];
        o[1] = (_Float16)t[kc+1][nr];
        o[2] = (_Float16)t[kc+2][nr];
        o[3] = (_Float16)t[kc+3][nr];
        *(f16x4*)&T[(size_t)(bn + nr) * EMB + bk + kc] = o;
    }
}

// ---------------------------------------------------------------------------
// MFMA GEMM core v6: R6-verified v3 structure (BM=64 x BN=128 x BK=64,
// 4 waves 2Mx2N, XOR-chunk swizzled LDS), templated on the A-source.
//   A32=false: fp16 A via global_load_lds, plain single-barrier dbuf loop
//     (R6-verified, 48us).
//   A32=true : fused fp32->fp16 A (saves the prep convert pass).  R13's
//     1-deep version stalled (qkv 72us: pending A loads consumed ~400cyc
//     after issue vs up-to-900cyc latency, and __syncthreads' vmcnt(0)
//     drain gave no in-flight slack).  v6 = 2-deep register prefetch +
//     counted vmcnt + raw s_barrier (the attn-v10-proven pattern): B-glds
//     issued BEFORE A-loads each step, boundary waits vmcnt(4) -> retires
//     B(t+1) in-order while A(t+2) stays in flight; pend A is >=1 full
//     iteration old at its use.  Loop fully unrolled (K=1024, NS=16) so
//     tail-wait selection folds at compile time.
// C = scale*(A @ Bt^T + bias)
// ---------------------------------------------------------------------------
template <bool A32>
__device__ __forceinline__
void gemm_core(const void* __restrict__ Aptr, const _Float16* __restrict__ Bt,
               const float* __restrict__ bias, float* __restrict__ Cf,
               _Float16* __restrict__ Ch, int M, int N,
               float scale, int mode, int bx, int by)
{
    constexpr int K  = 1024;          // both GEMMs have K = 1024
    constexpr int NS = K / 64;        // 16 K-steps

    __shared__ __align__(16) _Float16 As[2][64 * 64];    // 16 KB
    __shared__ __align__(16) _Float16 Bs[2][128 * 64];   // 32 KB

    const int tid  = threadIdx.x;
    const int lane = tid & 63;
    const int wave = tid >> 6;          // 0..3
    const int c    = lane & 15;
    const int quad = lane >> 4;
    const int bm   = by * 64;
    const int bn   = bx * 128;
    const int wm   = (wave >> 1) * 32;  // 2 waves in M
    const int wn   = (wave & 1) * 64;   // 2 waves in N

    f32x4 acc[2][4];
    #pragma unroll
    for (int i = 0; i < 2; ++i)
        #pragma unroll
        for (int j = 0; j < 4; ++j)
            #pragma unroll
            for (int r = 0; r < 4; ++r) acc[i][j][r] = 0.f;

    const size_t Kb = (size_t)K * 2;                     // fp16 row stride bytes
    const int    lc = ((tid & 7) ^ ((tid >> 3) & 7)) * 16;
    const char* gB = (const char*)Bt + (size_t)(bn + (tid >> 3)) * Kb + lc;

    const char*  gA16 = nullptr;
    const float* gA32 = nullptr;
    int aswz0 = 0, aswz1 = 0;
    if constexpr (A32) {
        const int ar  = tid >> 2;        // row 0..63
        const int acg = tid & 3;         // 16-col group
        gA32  = (const float*)Aptr + (size_t)(bm + ar) * K + acg * 16;
        aswz0 = ar * 64 + (((2*acg    ) ^ (ar & 7)) * 8);
        aswz1 = ar * 64 + (((2*acg + 1) ^ (ar & 7)) * 8);
    } else {
        gA16 = (const char*)Aptr + (size_t)(bm + (tid >> 3)) * Kb + lc;
    }

    auto stageB = [&](int buf, int t) {
        const size_t ko = (size_t)t * 128;               // 64 cols * 2 B
        char* lB = (char*)&Bs[buf][0] + wave * 1024;
        ASYNC_LD16(gB + ko,           lB);
        ASYNC_LD16(gB + 32*Kb + ko,   lB + 4096);
        ASYNC_LD16(gB + 64*Kb + ko,   lB + 8192);
        ASYNC_LD16(gB + 96*Kb + ko,   lB + 12288);
    };
    auto stageA16 = [&](int buf, int t) {
        const size_t ko = (size_t)t * 128;
        char* lA = (char*)&As[buf][0] + wave * 1024;
        ASYNC_LD16(gA16 + ko,         lA);
        ASYNC_LD16(gA16 + 32*Kb + ko, lA + 4096);
    };
    auto writeA32 = [&](int buf, const float4* a) {
        f16x8 h0, h1;
        h0[0] = (_Float16)a[0].x; h0[1] = (_Float16)a[0].y;
        h0[2] = (_Float16)a[0].z; h0[3] = (_Float16)a[0].w;
        h0[4] = (_Float16)a[1].x; h0[5] = (_Float16)a[1].y;
        h0[6] = (_Float16)a[1].z; h0[7] = (_Float16)a[1].w;
        h1[0] = (_Float16)a[2].x; h1[1] = (_Float16)a[2].y;
        h1[2] = (_Float16)a[2].z; h1[3] = (_Float16)a[2].w;
        h1[4] = (_Float16)a[3].x; h1[5] = (_Float16)a[3].y;
        h1[6] = (_Float16)a[3].z; h1[7] = (_Float16)a[3].w;
        *(f16x8*)&As[buf][aswz0] = h0;
        *(f16x8*)&As[buf][aswz1] = h1;
    };
    auto compute = [&](int cur) {
        #pragma unroll
        for (int kk = 0; kk < 2; ++kk) {
            f16x8 af[2], bf[4];
            #pragma unroll
            for (int i = 0; i < 2; ++i)
                af[i] = *(const f16x8*)
                    &As[cur][(wm + i*16 + c) * 64 + (((kk*4 + quad) ^ (c & 7)) * 8)];
            #pragma unroll
            for (int j = 0; j < 4; ++j)
                bf[j] = *(const f16x8*)
                    &Bs[cur][(wn + j*16 + c) * 64 + (((kk*4 + quad) ^ (c & 7)) * 8)];
            #pragma unroll
            for (int i = 0; i < 2; ++i)
                #pragma unroll
                for (int j = 0; j < 4; ++j)
                    acc[i][j] = __builtin_amdgcn_mfma_f32_16x16x32_f16(af[i], bf[j], acc[i][j], 0, 0, 0);
        }
    };

    if constexpr (A32) {
        float4 pend[4];
        // --- prologue: A(0) -> As[0], B(0) staged, A(1) left in flight.
        {
            float4 c0[4];
            #pragma unroll
            for (int i = 0; i < 4; ++i) c0[i] = *(const float4*)(gA32 + i*4);
            stageB(0, 0);
            #pragma unroll
            for (int i = 0; i < 4; ++i) pend[i] = *(const float4*)(gA32 + 64 + i*4);
            writeA32(0, c0);    // auto vmcnt wait retires A(0) only (in-order)
            asm volatile("s_waitcnt lgkmcnt(0)" ::: "memory");
            asm volatile("s_waitcnt vmcnt(4)" ::: "memory");   // retire B(0); A(1) stays
            __builtin_amdgcn_s_barrier();
            asm volatile("" ::: "memory");
        }
        #pragma unroll
        for (int t = 0; t < NS; ++t) {
            const int cur = t & 1;
            if (t + 1 < NS) stageB(cur ^ 1, t + 1);   // B first (in-order retire)
            float4 nxt[4];
            if (t + 2 < NS) {
                const float* p = gA32 + (size_t)(t + 2) * 64;
                #pragma unroll
                for (int i = 0; i < 4; ++i) nxt[i] = *(const float4*)(p + i*4);
            }
            compute(cur);
            if (t + 1 < NS) {
                writeA32(cur ^ 1, pend);   // pend = A(t+1), >=1 iteration old
                asm volatile("s_waitcnt lgkmcnt(0)" ::: "memory");
                if (t + 2 < NS) {
                    asm volatile("s_waitcnt vmcnt(4)" ::: "memory"); // B(t+1) done, A(t+2) flies
                } else {
                    asm volatile("s_waitcnt vmcnt(0)" ::: "memory"); // tail: drain B(NS-1)
                }
                __builtin_amdgcn_s_barrier();
                asm volatile("" ::: "memory");
                if (t + 2 < NS) {
                    #pragma unroll
                    for (int i = 0; i < 4; ++i) pend[i] = nxt[i];
                }
            }
        }
    } else {
        // --- R6-verified plain dbuf loop (fp16 A via glds) ---
        stageA16(0, 0);
        stageB(0, 0);
        __syncthreads();
        int cur = 0;
        for (int t = 0; t < NS; ++t) {
            if (t + 1 < NS) { stageA16(cur ^ 1, t + 1); stageB(cur ^ 1, t + 1); }
            compute(cur);
            __syncthreads();
            cur ^= 1;
        }
    }

    float bcol[4];
    #pragma unroll
    for (int j = 0; j < 4; ++j) bcol[j] = bias[bn + wn + j * 16 + c];

    #pragma unroll
    for (int i = 0; i < 2; ++i) {
        int m0 = bm + wm + i * 16 + quad * 4;
        #pragma unroll
        for (int j = 0; j < 4; ++j) {
            int n = bn + wn + j * 16 + c;
            if (mode == 0) {
                #pragma unroll
                for (int r = 0; r < 4; ++r)
                    Cf[(size_t)(m0 + r) * N + n] = acc[i][j][r] + bcol[j];
            } else if (mode == 1) {
                int h = n >> 6, d = n & 63;
                #pragma unroll
                for (int r = 0; r < 4; ++r) {
                    int mm = m0 + r;
                    int b = mm >> 11, l = mm & (SLEN - 1);
                    Ch[(((size_t)(b * NH + h)) * SLEN + l) * DM + d] =
                        (_Float16)((acc[i][j][r] + bcol[j]) * scale);
                }
            } else {
                int h = n >> 6, d = n & 63;
                int b = m0 >> 11, l = m0 & (SLEN - 1);
                f16x4 o;
                #pragma unroll
                for (int r = 0; r < 4; ++r)
                    o[r] = (_Float16)(acc[i][j][r] + bcol[j]);
                *(f16x4*)&Ch[(((size_t)(b * NH + h)) * DM + d) * SLEN + l] = o;
            }
        }
    }
}

// XCD-bijective block swizzle: all 8 N-blocks sharing an A-panel (same by)
// get the same wid%8 -> same XCD L2 -> A fetched once per XCD, not 8x.
__device__ __forceinline__ void xcd_swz(int& bx, int& by)
{
    int wid = blockIdx.x + 8 * blockIdx.y;   // 0..511, = flat wg id per z
    bx = wid >> 6;                           // 0..7
    by = wid & 63;                           // 0..63
}

__global__ __launch_bounds__(256)
void gemm_qkv(const float* __restrict__ Q, const float* __restrict__ K,
              const float* __restrict__ V,
              const _Float16* __restrict__ WqT, const _Float16* __restrict__ WkT,
              const _Float16* __restrict__ WvT,
              const float* __restrict__ bq, const float* __restrict__ bk,
              const float* __restrict__ bv,
              _Float16* __restrict__ q_ws, _Float16* __restrict__ k_ws,
              _Float16* __restrict__ v_ws)
{
    const float* A;
    const _Float16* Bt;
    const float* bias;
    _Float16* Ch;
    float scale;
    int mode;
    // q-scale folds 1/sqrt(DM) AND log2(e) so attention can use exp2 directly.
    if (blockIdx.z == 0)      { A = Q; Bt = WqT; bias = bq; Ch = q_ws; scale = 0.18033688f; mode = 1; }
    else if (blockIdx.z == 1) { A = K; Bt = WkT; bias = bk; Ch = k_ws; scale = 1.0f;        mode = 1; }
    else                      { A = V; Bt = WvT; bias = bv; Ch = v_ws; scale = 1.0f;        mode = 2; }
    int bx, by; xcd_swz(bx, by);
    gemm_core<true>(A, Bt, bias, nullptr, Ch, BS * SLEN, NH * DM, scale, mode, bx, by);
}

__global__ __launch_bounds__(256)
void gemm_out(const _Float16* __restrict__ Oh, const _Float16* __restrict__ WoT,
              const float* __restrict__ bo, float* __restrict__ out)
{
    int bx, by; xcd_swz(bx, by);
    gemm_core<false>(Oh, WoT, bo, out, nullptr, BS * SLEN, EMB, 1.0f, 0, bx, by);
}

// ---------------------------------------------------------------------------
// MFMA flash attention v10 (R8-verified, 47.5us / 34% occ): 8 waves =
// 4 q-groups (32 rows) x 2 key-halves (32 keys); all-K=32 MFMA; no-max
// exp2 softmax; XOR-chunk-swizzled LDS; 4-deep LDS ring with counted-vmcnt
// boundaries (prefetch 3 ahead, s_waitcnt vmcnt(4) + raw s_barrier).
// qw/kw: [b][h][l][d] fp16;  vwT: [b][h][d][l] fp16;  ow: [b][l][h*64+d] fp16
// ---------------------------------------------------------------------------
__global__ __launch_bounds__(512)
void attn_mfma(const _Float16* __restrict__ qw, const _Float16* __restrict__ kw,
               const _Float16* __restrict__ vwT, _Float16* __restrict__ ow)
{
    // swizzled: element (row, col) at row*64 + ((col/8 ^ (row&7))*8 + col%8)
    __shared__ __align__(16) _Float16 Kt[4][64 * 64];   // [key][d], 32 KB ring
    __shared__ __align__(16) _Float16 Vt[4][64 * 64];   // [d][key], 32 KB ring

    const int tid  = threadIdx.x;
    const int lane = tid & 63;
    const int wave = tid >> 6;          // 0..7
    const int c    = lane & 15;
    const int quad = lane >> 4;
    const int qg   = wave & 3;          // q-group: 32 rows
    const int kh   = wave >> 2;         // key-half: 32 keys
    const int bh   = blockIdx.y;
    const int b    = bh >> 4;
    const int h    = bh & 15;
    const int qbase = blockIdx.x * 128 + qg * 32;

    const _Float16* kb = kw  + (size_t)bh * SLEN * DM;
    const _Float16* vb = vwT + (size_t)bh * DM * SLEN;
    const _Float16* qb = qw  + (size_t)bh * SLEN * DM;

    // Q fragments (B-operand of S^T = K Q^T): lane: qrow = t*16+c, d = ch*32+quad*8+j
    f16x8 qf[2][2];
    #pragma unroll
    for (int t = 0; t < 2; ++t)
        #pragma unroll
        for (int ch = 0; ch < 2; ++ch)
            qf[t][ch] = *(const f16x8*)(qb + (size_t)(qbase + t*16 + c) * DM + ch*32 + quad*8);

    f32x4 oacc[2][4];
    f32x4 lacc[2];
    #pragma unroll
    for (int t = 0; t < 2; ++t) {
        #pragma unroll
        for (int dg = 0; dg < 4; ++dg)
            #pragma unroll
            for (int r = 0; r < 4; ++r) oacc[t][dg][r] = 0.f;
        #pragma unroll
        for (int r = 0; r < 4; ++r) lacc[t][r] = 0.f;
    }

    const f16x8 ones8 = {(_Float16)1.f, (_Float16)1.f, (_Float16)1.f, (_Float16)1.f,
                         (_Float16)1.f, (_Float16)1.f, (_Float16)1.f, (_Float16)1.f};
    const f32x4 zero4 = {0.f, 0.f, 0.f, 0.f};

    // --- global_load_lds staging (per wave: 1 K-load + 1 V-load per tile;
    // lane's 16 B at dest row w*8 + lane/8, phys chunk lane&7; source holds
    // the swizzled chunk (lane&7) ^ (row&7), row&7 = (lane>>3)&7).
    const int r0  = wave * 8 + (lane >> 3);
    const int lc0 = (((lane & 7) ^ ((lane >> 3) & 7)) * 16);
    const char* gk = (const char*)kb + r0 * 128 + lc0;             // K row stride 128 B
    const char* gv = (const char*)vb + (size_t)r0 * 4096 + lc0;    // V^T row stride 4096 B

    auto stage = [&](int buf) {
        char* pk = (char*)&Kt[buf][0] + wave * 1024;
        char* pv = (char*)&Vt[buf][0] + wave * 1024;
        ASYNC_LD16(gk, pk);
        ASYNC_LD16(gv, pv);
        gk += 8192;   // 64 keys * 128 B
        gv += 128;    // 64 keys * 2 B per d-row
    };

    // prologue: fill ring slots 0,1,2 (6 loads/wave outstanding)
    stage(0); stage(1); stage(2);
    asm volatile("s_waitcnt vmcnt(4)" ::: "memory");   // slot 0 landed
    __builtin_amdgcn_s_barrier();
    asm volatile("" ::: "memory");

    const int NT = SLEN / 64;
    for (int t = 0; t < NT; ++t) {
        stage((t + 3) & 3);      // 3 tiles ahead (tail over-reads stay in ws)
        const int cb = t & 3;

        // K fragments (A-operand) for this wave's key-half:
        // key = kh*32 + kg*16 + c, logical chunk ch*4+quad (row&7 = c&7)
        f16x8 kf[2][2];
        #pragma unroll
        for (int kg = 0; kg < 2; ++kg)
            #pragma unroll
            for (int ch = 0; ch < 2; ++ch)
                kf[kg][ch] = *(const f16x8*)
                    &Kt[cb][(kh*32 + kg*16 + c) * 64 + (((ch*4 + quad) ^ (c & 7)) * 8)];

        // S^T = K Q^T : lane: key = kh*32 + kg*16 + quad*4 + r, qrow = t2*16+c
        f32x4 s[2][2];
        #pragma unroll
        for (int t2 = 0; t2 < 2; ++t2)
            #pragma unroll
            for (int kg = 0; kg < 2; ++kg) {
                s[t2][kg] = __builtin_amdgcn_mfma_f32_16x16x32_f16(kf[kg][0], qf[t2][0], zero4,     0, 0, 0);
                s[t2][kg] = __builtin_amdgcn_mfma_f32_16x16x32_f16(kf[kg][1], qf[t2][1], s[t2][kg], 0, 0, 0);
            }

        // p = 2^(s') packed into the K=32 A-fragment order: pf8[t2] element j
        // holds key (rel. to kh*32) = (j>=4)*16 + quad*4 + (j&3)
        f16x8 pf8[2];
        #pragma unroll
        for (int t2 = 0; t2 < 2; ++t2) {
            hf4 h4[2];
            #pragma unroll
            for (int u = 0; u < 2; ++u) {
                float p0 = __builtin_amdgcn_exp2f(s[t2][u][0]);
                float p1 = __builtin_amdgcn_exp2f(s[t2][u][1]);
                float p2 = __builtin_amdgcn_exp2f(s[t2][u][2]);
                float p3 = __builtin_amdgcn_exp2f(s[t2][u][3]);
                hf2 lo = __builtin_amdgcn_cvt_pkrtz(p0, p1);
                hf2 hi = __builtin_amdgcn_cvt_pkrtz(p2, p3);
                h4[u] = __builtin_shufflevector(lo, hi, 0, 1, 2, 3);
            }
            hf8 h8 = __builtin_shufflevector(h4[0], h4[1], 0, 1, 2, 3, 4, 5, 6, 7);
            pf8[t2] = __builtin_bit_cast(f16x8, h8);
        }

        // l += P @ ones  (K=32; with B = ones any k-permutation is valid)
        #pragma unroll
        for (int t2 = 0; t2 < 2; ++t2)
            lacc[t2] = __builtin_amdgcn_mfma_f32_16x16x32_f16(pf8[t2], ones8, lacc[t2], 0, 0, 0);

        // O += P V  (K=32: B element j = V[kh*32 + key(quad,j)][d=dg*16+c])
        #pragma unroll
        for (int dg = 0; dg < 4; ++dg) {
            f16x4 vf[2];
            #pragma unroll
            for (int u = 0; u < 2; ++u)
                vf[u] = *(const f16x4*)
                    &Vt[cb][(dg*16 + c) * 64 +
                            (((kh*4 + 2*u + (quad >> 1)) ^ (c & 7)) * 8) + (quad & 1) * 4];
            f16x8 v8 = __builtin_shufflevector(vf[0], vf[1], 0, 1, 2, 3, 4, 5, 6, 7);
            #pragma unroll
            for (int t2 = 0; t2 < 2; ++t2)
                oacc[t2][dg] = __builtin_amdgcn_mfma_f32_16x16x32_f16(pf8[t2], v8, oacc[t2][dg], 0, 0, 0);
        }

        // tile boundary: counted wait (newest 2 tiles' loads stay in flight)
        asm volatile("s_waitcnt vmcnt(4)" ::: "memory");
        __builtin_amdgcn_s_barrier();
        asm volatile("" ::: "memory");
    }

    __syncthreads();   // drain all outstanding loads before LDS reuse

    // --- merge key-half partials (O, l) through LDS, two rounds over t.
    // Round size: 4 qg x 64 lanes x 20 f32 = 20 KB (fits in Kt's 32 KB).
    float* mb = (float*)&Kt[0][0];
    #pragma unroll
    for (int t = 0; t < 2; ++t) {
        if (kh == 1) {
            float* p = mb + ((qg * 64 + lane) * 20);
            *(f32x4*)(p +  0) = oacc[t][0];
            *(f32x4*)(p +  4) = oacc[t][1];
            *(f32x4*)(p +  8) = oacc[t][2];
            *(f32x4*)(p + 12) = oacc[t][3];
            *(f32x4*)(p + 16) = lacc[t];
        }
        __syncthreads();
        if (kh == 0) {
            const float* p = mb + ((qg * 64 + lane) * 20);
            f32x4 po[4], pl;
            po[0] = *(const f32x4*)(p +  0);
            po[1] = *(const f32x4*)(p +  4);
            po[2] = *(const f32x4*)(p +  8);
            po[3] = *(const f32x4*)(p + 12);
            pl    = *(const f32x4*)(p + 16);
            #pragma unroll
            for (int r = 0; r < 4; ++r) {
                float linv = 1.0f / (lacc[t][r] + pl[r]);
                int row = qbase + t*16 + quad*4 + r;
                #pragma unroll
                for (int dg = 0; dg < 4; ++dg)
                    ow[((size_t)b * SLEN + row) * EMB + h * DM + dg*16 + c] =
                        (_Float16)((oacc[t][dg][r] + po[dg][r]) * linv);
            }
        }
        __syncthreads();
    }
}

// ---------------------------------------------------------------------------
extern "C" void kernel_launch(void* const* d_in, const int* in_sizes, int n_in,
                              void* d_out, int out_size, void* d_ws, size_t ws_size,
                              hipStream_t stream)
{
    const float* Q  = (const float*)d_in[0];
    const float* K  = (const float*)d_in[1];
    const float* V  = (const float*)d_in[2];
    const float* Wq = (const float*)d_in[3];
    const float* bq = (const float*)d_in[4];
    const float* Wk = (const float*)d_in[5];
    const float* bk = (const float*)d_in[6];
    const float* Wv = (const float*)d_in[7];
    const float* bv = (const float*)d_in[8];
    const float* Wo = (const float*)d_in[9];
    const float* bo = (const float*)d_in[10];
    float* out = (float*)d_out;

    const size_t MN = (size_t)BS * SLEN * NH * DM;   // 4M halves
    const size_t WW = (size_t)EMB * NH * DM;         // 1M halves

    _Float16* base = (_Float16*)d_ws;
    _Float16* WqT  = base;
    _Float16* WkT  = WqT + WW;
    _Float16* WvT  = WkT + WW;
    _Float16* WoT  = WvT + WW;
    _Float16* q_ws = WoT + WW;
    _Float16* k_ws = q_ws + MN;
    _Float16* v_ws = k_ws + MN;
    _Float16* o_ws = v_ws + MN;

    dim3 blk(256);

    prep<<<dim3(256, 1, 4), blk, 0, stream>>>(Wq, Wk, Wv, Wo,
                                              WqT, WkT, WvT, WoT);

    gemm_qkv<<<dim3(8, 64, 3), blk, 0, stream>>>(Q, K, V, WqT, WkT, WvT,
                                                 bq, bk, bv, q_ws, k_ws, v_ws);

    attn_mfma<<<dim3(SLEN / 128, BS * NH), dim3(512), 0, stream>>>(q_ws, k_ws, v_ws, o_ws);

    gemm_out<<<dim3(8, 64, 1), blk, 0, stream>>>(o_ws, WoT, bo, out);
}

// Round 15
// 222.658 us; speedup vs baseline: 1.0397x; 1.0134x over previous
//
#include <hip/hip_runtime.h>
#include <cstdint>
#include <cstddef>

#define EMB  1024
#define DM   64
#define NH   16
#define SLEN 2048
#define BS   2

typedef _Float16 f16x8 __attribute__((ext_vector_type(8)));
typedef _Float16 f16x4 __attribute__((ext_vector_type(4)));
typedef __fp16   hf2   __attribute__((ext_vector_type(2)));
typedef __fp16   hf4   __attribute__((ext_vector_type(4)));
typedef __fp16   hf8   __attribute__((ext_vector_type(8)));
typedef float    f32x4 __attribute__((ext_vector_type(4)));

#define ASYNC_LD16(gp, lp)                                                        \
    __builtin_amdgcn_global_load_lds(                                             \
        (const __attribute__((address_space(1))) void*)(gp),                      \
        (__attribute__((address_space(3))) void*)(lp), 16, 0, 0)

// ---------------------------------------------------------------------------
// prep: z<3 -> fp32->fp16 flat convert of Q/K/V; z>=3 -> weight transpose
// convert W[K][N] fp32 -> W^T[N][K] fp16 (z-3 selects among 4 weights).
// (R13/R14's attempt to fuse the QKV convert into gemm_qkv's A-staging cost
// +18us in qkv vs the ~12us this pass costs -- reverted.)
// ---------------------------------------------------------------------------
__global__ __launch_bounds__(256)
void prep(const float* __restrict__ Q, const float* __restrict__ K,
          const float* __restrict__ V,
          const float* __restrict__ Wq, const float* __restrict__ Wk,
          const float* __restrict__ Wv, const float* __restrict__ Wo,
          _Float16* __restrict__ Qh, _Float16* __restrict__ Kh,
          _Float16* __restrict__ Vh,
          _Float16* __restrict__ WqT, _Float16* __restrict__ WkT,
          _Float16* __restrict__ WvT, _Float16* __restrict__ WoT)
{
    __shared__ float t[64][65];
    const int z = blockIdx.z;
    if (z < 3) {
        const float* in  = (z == 0) ? Q : (z == 1) ? K : V;
        _Float16*    out = (z == 0) ? Qh : (z == 1) ? Kh : Vh;
        size_t i = ((size_t)blockIdx.x * 256 + threadIdx.x) * 8;
        float4 a = *(const float4*)(in + i);
        float4 b = *(const float4*)(in + i + 4);
        f16x8 o;
        o[0] = (_Float16)a.x; o[1] = (_Float16)a.y; o[2] = (_Float16)a.z; o[3] = (_Float16)a.w;
        o[4] = (_Float16)b.x; o[5] = (_Float16)b.y; o[6] = (_Float16)b.z; o[7] = (_Float16)b.w;
        *(f16x8*)(out + i) = o;
        return;
    }
    if (blockIdx.x >= 256) return;
    const float* W;
    _Float16*    T;
    switch (z - 3) {
        case 0:  W = Wq; T = WqT; break;
        case 1:  W = Wk; T = WkT; break;
        case 2:  W = Wv; T = WvT; break;
        default: W = Wo; T = WoT; break;
    }
    const int tid = threadIdx.x;
    const int bn  = (blockIdx.x & 15) * 64;
    const int bk  = (blockIdx.x >> 4) * 64;

    #pragma unroll
    for (int p = 0; p < 4; ++p) {
        int row = p * 16 + (tid >> 4);
        int col = (tid & 15) * 4;
        float4 v = *(const float4*)(W + (size_t)(bk + row) * EMB + bn + col);
        t[row][col+0] = v.x; t[row][col+1] = v.y; t[row][col+2] = v.z; t[row][col+3] = v.w;
    }
    __syncthreads();
    #pragma unroll
    for (int p = 0; p < 4; ++p) {
        int nr = p * 16 + (tid >> 4);
        int kc = (tid & 15) * 4;
        f16x4 o;
        o[0] = (_Float16)t[kc+0][nr];
        o[1] = (_Float16)t[kc+1][nr];
        o[2] = (_Float16)t[kc+2][nr];
        o[3] = (_Float16)t[kc+3][nr];
        *(f16x4*)&T[(size_t)(bn + nr) * EMB + bk + kc] = o;
    }
}

// ---------------------------------------------------------------------------
// MFMA GEMM core v3 (R6/R12-verified, the two best totals): BM=64 x BN=128
// x BK=64, 4 waves (2M x 2N), XOR-chunk swizzled LDS, single-barrier
// double-buffered pipeline:
//   STAGE(buf^1, t+1)  ->  ds_read+MFMA on buf  ->  __syncthreads()
// C = scale*(A @ Bt^T + bias)
// ---------------------------------------------------------------------------
__device__ __forceinline__
void gemm_core(const _Float16* __restrict__ A, const _Float16* __restrict__ Bt,
               const float* __restrict__ bias, float* __restrict__ Cf,
               _Float16* __restrict__ Ch, int M, int N, int K,
               float scale, int mode, int bx, int by)
{
    __shared__ __align__(16) _Float16 As[2][64 * 64];    // 16 KB
    __shared__ __align__(16) _Float16 Bs[2][128 * 64];   // 32 KB

    const int tid  = threadIdx.x;
    const int lane = tid & 63;
    const int wave = tid >> 6;          // 0..3
    const int c    = lane & 15;
    const int quad = lane >> 4;
    const int bm   = by * 64;
    const int bn   = bx * 128;
    const int wm   = (wave >> 1) * 32;  // 2 waves in M
    const int wn   = (wave & 1) * 64;   // 2 waves in N

    f32x4 acc[2][4];
    #pragma unroll
    for (int i = 0; i < 2; ++i)
        #pragma unroll
        for (int j = 0; j < 4; ++j)
            #pragma unroll
            for (int r = 0; r < 4; ++r) acc[i][j][r] = 0.f;

    // staging: thread tid deposits 16 B at dest row R+(tid>>3), phys chunk
    // tid&7.  Source supplies logical chunk (tid&7)^(row&7) so LDS phys
    // chunk p of row r holds logical chunk p^(r&7).
    const size_t Kb = (size_t)K * 2;                     // row stride bytes
    const int    lc = ((tid & 7) ^ ((tid >> 3) & 7)) * 16;
    const char* gA = (const char*)A  + (size_t)(bm + (tid >> 3)) * Kb + lc;
    const char* gB = (const char*)Bt + (size_t)(bn + (tid >> 3)) * Kb + lc;

    const int NS = K / 64;

    auto stage = [&](int buf, int t) {
        const size_t ko = (size_t)t * 128;               // 64 cols * 2 B
        char* lA = (char*)&As[buf][0] + wave * 1024;
        char* lB = (char*)&Bs[buf][0] + wave * 1024;
        ASYNC_LD16(gA + ko,           lA);
        ASYNC_LD16(gA + 32*Kb + ko,   lA + 4096);
        ASYNC_LD16(gB + ko,           lB);
        ASYNC_LD16(gB + 32*Kb + ko,   lB + 4096);
        ASYNC_LD16(gB + 64*Kb + ko,   lB + 8192);
        ASYNC_LD16(gB + 96*Kb + ko,   lB + 12288);
    };

    stage(0, 0);
    __syncthreads();                   // drain prologue loads

    int cur = 0;
    for (int t = 0; t < NS; ++t) {
        if (t + 1 < NS) stage(cur ^ 1, t + 1);   // loads fly during compute

        #pragma unroll
        for (int kk = 0; kk < 2; ++kk) {
            f16x8 af[2], bf[4];
            #pragma unroll
            for (int i = 0; i < 2; ++i)
                af[i] = *(const f16x8*)
                    &As[cur][(wm + i*16 + c) * 64 + (((kk*4 + quad) ^ (c & 7)) * 8)];
            #pragma unroll
            for (int j = 0; j < 4; ++j)
                bf[j] = *(const f16x8*)
                    &Bs[cur][(wn + j*16 + c) * 64 + (((kk*4 + quad) ^ (c & 7)) * 8)];
            #pragma unroll
            for (int i = 0; i < 2; ++i)
                #pragma unroll
                for (int j = 0; j < 4; ++j)
                    acc[i][j] = __builtin_amdgcn_mfma_f32_16x16x32_f16(af[i], bf[j], acc[i][j], 0, 0, 0);
        }
        __syncthreads();               // vmcnt(0)+barrier: next buf ready
        cur ^= 1;
    }

    float bcol[4];
    #pragma unroll
    for (int j = 0; j < 4; ++j) bcol[j] = bias[bn + wn + j * 16 + c];

    #pragma unroll
    for (int i = 0; i < 2; ++i) {
        int m0 = bm + wm + i * 16 + quad * 4;
        #pragma unroll
        for (int j = 0; j < 4; ++j) {
            int n = bn + wn + j * 16 + c;
            if (mode == 0) {
                #pragma unroll
                for (int r = 0; r < 4; ++r)
                    Cf[(size_t)(m0 + r) * N + n] = acc[i][j][r] + bcol[j];
            } else if (mode == 1) {
                int h = n >> 6, d = n & 63;
                #pragma unroll
                for (int r = 0; r < 4; ++r) {
                    int mm = m0 + r;
                    int b = mm >> 11, l = mm & (SLEN - 1);
                    Ch[(((size_t)(b * NH + h)) * SLEN + l) * DM + d] =
                        (_Float16)((acc[i][j][r] + bcol[j]) * scale);
                }
            } else {
                int h = n >> 6, d = n & 63;
                int b = m0 >> 11, l = m0 & (SLEN - 1);
                f16x4 o;
                #pragma unroll
                for (int r = 0; r < 4; ++r)
                    o[r] = (_Float16)(acc[i][j][r] + bcol[j]);
                *(f16x4*)&Ch[(((size_t)(b * NH + h)) * DM + d) * SLEN + l] = o;
            }
        }
    }
}

// XCD-bijective block swizzle: all 8 N-blocks sharing an A-panel (same by)
// get the same wid%8 -> same XCD L2 -> A fetched once per XCD, not 8x.
__device__ __forceinline__ void xcd_swz(int& bx, int& by)
{
    int wid = blockIdx.x + 8 * blockIdx.y;   // 0..511, = flat wg id per z
    bx = wid >> 6;                           // 0..7
    by = wid & 63;                           // 0..63
}

__global__ __launch_bounds__(256)
void gemm_qkv(const _Float16* __restrict__ Qh, const _Float16* __restrict__ Kh,
              const _Float16* __restrict__ Vh,
              const _Float16* __restrict__ WqT, const _Float16* __restrict__ WkT,
              const _Float16* __restrict__ WvT,
              const float* __restrict__ bq, const float* __restrict__ bk,
              const float* __restrict__ bv,
              _Float16* __restrict__ q_ws, _Float16* __restrict__ k_ws,
              _Float16* __restrict__ v_ws)
{
    const _Float16 *A, *Bt;
    const float* bias;
    _Float16* Ch;
    float scale;
    int mode;
    // q-scale folds 1/sqrt(DM) AND log2(e) so attention can use exp2 directly.
    if (blockIdx.z == 0)      { A = Qh; Bt = WqT; bias = bq; Ch = q_ws; scale = 0.18033688f; mode = 1; }
    else if (blockIdx.z == 1) { A = Kh; Bt = WkT; bias = bk; Ch = k_ws; scale = 1.0f;        mode = 1; }
    else                      { A = Vh; Bt = WvT; bias = bv; Ch = v_ws; scale = 1.0f;        mode = 2; }
    int bx, by; xcd_swz(bx, by);
    gemm_core(A, Bt, bias, nullptr, Ch, BS * SLEN, NH * DM, EMB, scale, mode, bx, by);
}

__global__ __launch_bounds__(256)
void gemm_out(const _Float16* __restrict__ Oh, const _Float16* __restrict__ WoT,
              const float* __restrict__ bo, float* __restrict__ out)
{
    int bx, by; xcd_swz(bx, by);
    gemm_core(Oh, WoT, bo, out, nullptr, BS * SLEN, EMB, NH * DM, 1.0f, 0, bx, by);
}

// ---------------------------------------------------------------------------
// MFMA flash attention v10 (R8-verified, 47.5us / 34% occ): 8 waves =
// 4 q-groups (32 rows) x 2 key-halves (32 keys); all-K=32 MFMA; no-max
// exp2 softmax; XOR-chunk-swizzled LDS; 4-deep LDS ring with counted-vmcnt
// boundaries (prefetch 3 ahead, s_waitcnt vmcnt(4) + raw s_barrier).
// qw/kw: [b][h][l][d] fp16;  vwT: [b][h][d][l] fp16;  ow: [b][l][h*64+d] fp16
// ---------------------------------------------------------------------------
__global__ __launch_bounds__(512)
void attn_mfma(const _Float16* __restrict__ qw, const _Float16* __restrict__ kw,
               const _Float16* __restrict__ vwT, _Float16* __restrict__ ow)
{
    // swizzled: element (row, col) at row*64 + ((col/8 ^ (row&7))*8 + col%8)
    __shared__ __align__(16) _Float16 Kt[4][64 * 64];   // [key][d], 32 KB ring
    __shared__ __align__(16) _Float16 Vt[4][64 * 64];   // [d][key], 32 KB ring

    const int tid  = threadIdx.x;
    const int lane = tid & 63;
    const int wave = tid >> 6;          // 0..7
    const int c    = lane & 15;
    const int quad = lane >> 4;
    const int qg   = wave & 3;          // q-group: 32 rows
    const int kh   = wave >> 2;         // key-half: 32 keys
    const int bh   = blockIdx.y;
    const int b    = bh >> 4;
    const int h    = bh & 15;
    const int qbase = blockIdx.x * 128 + qg * 32;

    const _Float16* kb = kw  + (size_t)bh * SLEN * DM;
    const _Float16* vb = vwT + (size_t)bh * DM * SLEN;
    const _Float16* qb = qw  + (size_t)bh * SLEN * DM;

    // Q fragments (B-operand of S^T = K Q^T): lane: qrow = t*16+c, d = ch*32+quad*8+j
    f16x8 qf[2][2];
    #pragma unroll
    for (int t = 0; t < 2; ++t)
        #pragma unroll
        for (int ch = 0; ch < 2; ++ch)
            qf[t][ch] = *(const f16x8*)(qb + (size_t)(qbase + t*16 + c) * DM + ch*32 + quad*8);

    f32x4 oacc[2][4];
    f32x4 lacc[2];
    #pragma unroll
    for (int t = 0; t < 2; ++t) {
        #pragma unroll
        for (int dg = 0; dg < 4; ++dg)
            #pragma unroll
            for (int r = 0; r < 4; ++r) oacc[t][dg][r] = 0.f;
        #pragma unroll
        for (int r = 0; r < 4; ++r) lacc[t][r] = 0.f;
    }

    const f16x8 ones8 = {(_Float16)1.f, (_Float16)1.f, (_Float16)1.f, (_Float16)1.f,
                         (_Float16)1.f, (_Float16)1.f, (_Float16)1.f, (_Float16)1.f};
    const f32x4 zero4 = {0.f, 0.f, 0.f, 0.f};

    // --- global_load_lds staging (per wave: 1 K-load + 1 V-load per tile;
    // lane's 16 B at dest row w*8 + lane/8, phys chunk lane&7; source holds
    // the swizzled chunk (lane&7) ^ (row&7), row&7 = (lane>>3)&7).
    const int r0  = wave * 8 + (lane >> 3);
    const int lc0 = (((lane & 7) ^ ((lane >> 3) & 7)) * 16);
    const char* gk = (const char*)kb + r0 * 128 + lc0;             // K row stride 128 B
    const char* gv = (const char*)vb + (size_t)r0 * 4096 + lc0;    // V^T row stride 4096 B

    auto stage = [&](int buf) {
        char* pk = (char*)&Kt[buf][0] + wave * 1024;
        char* pv = (char*)&Vt[buf][0] + wave * 1024;
        ASYNC_LD16(gk, pk);
        ASYNC_LD16(gv, pv);
        gk += 8192;   // 64 keys * 128 B
        gv += 128;    // 64 keys * 2 B per d-row
    };

    // prologue: fill ring slots 0,1,2 (6 loads/wave outstanding)
    stage(0); stage(1); stage(2);
    asm volatile("s_waitcnt vmcnt(4)" ::: "memory");   // slot 0 landed
    __builtin_amdgcn_s_barrier();
    asm volatile("" ::: "memory");

    const int NT = SLEN / 64;
    for (int t = 0; t < NT; ++t) {
        stage((t + 3) & 3);      // 3 tiles ahead (tail over-reads stay in ws)
        const int cb = t & 3;

        // K fragments (A-operand) for this wave's key-half:
        // key = kh*32 + kg*16 + c, logical chunk ch*4+quad (row&7 = c&7)
        f16x8 kf[2][2];
        #pragma unroll
        for (int kg = 0; kg < 2; ++kg)
            #pragma unroll
            for (int ch = 0; ch < 2; ++ch)
                kf[kg][ch] = *(const f16x8*)
                    &Kt[cb][(kh*32 + kg*16 + c) * 64 + (((ch*4 + quad) ^ (c & 7)) * 8)];

        // S^T = K Q^T : lane: key = kh*32 + kg*16 + quad*4 + r, qrow = t2*16+c
        f32x4 s[2][2];
        #pragma unroll
        for (int t2 = 0; t2 < 2; ++t2)
            #pragma unroll
            for (int kg = 0; kg < 2; ++kg) {
                s[t2][kg] = __builtin_amdgcn_mfma_f32_16x16x32_f16(kf[kg][0], qf[t2][0], zero4,     0, 0, 0);
                s[t2][kg] = __builtin_amdgcn_mfma_f32_16x16x32_f16(kf[kg][1], qf[t2][1], s[t2][kg], 0, 0, 0);
            }

        // p = 2^(s') packed into the K=32 A-fragment order: pf8[t2] element j
        // holds key (rel. to kh*32) = (j>=4)*16 + quad*4 + (j&3)
        f16x8 pf8[2];
        #pragma unroll
        for (int t2 = 0; t2 < 2; ++t2) {
            hf4 h4[2];
            #pragma unroll
            for (int u = 0; u < 2; ++u) {
                float p0 = __builtin_amdgcn_exp2f(s[t2][u][0]);
                float p1 = __builtin_amdgcn_exp2f(s[t2][u][1]);
                float p2 = __builtin_amdgcn_exp2f(s[t2][u][2]);
                float p3 = __builtin_amdgcn_exp2f(s[t2][u][3]);
                hf2 lo = __builtin_amdgcn_cvt_pkrtz(p0, p1);
                hf2 hi = __builtin_amdgcn_cvt_pkrtz(p2, p3);
                h4[u] = __builtin_shufflevector(lo, hi, 0, 1, 2, 3);
            }
            hf8 h8 = __builtin_shufflevector(h4[0], h4[1], 0, 1, 2, 3, 4, 5, 6, 7);
            pf8[t2] = __builtin_bit_cast(f16x8, h8);
        }

        // l += P @ ones  (K=32; with B = ones any k-permutation is valid)
        #pragma unroll
        for (int t2 = 0; t2 < 2; ++t2)
            lacc[t2] = __builtin_amdgcn_mfma_f32_16x16x32_f16(pf8[t2], ones8, lacc[t2], 0, 0, 0);

        // O += P V  (K=32: B element j = V[kh*32 + key(quad,j)][d=dg*16+c])
        #pragma unroll
        for (int dg = 0; dg < 4; ++dg) {
            f16x4 vf[2];
            #pragma unroll
            for (int u = 0; u < 2; ++u)
                vf[u] = *(const f16x4*)
                    &Vt[cb][(dg*16 + c) * 64 +
                            (((kh*4 + 2*u + (quad >> 1)) ^ (c & 7)) * 8) + (quad & 1) * 4];
            f16x8 v8 = __builtin_shufflevector(vf[0], vf[1], 0, 1, 2, 3, 4, 5, 6, 7);
            #pragma unroll
            for (int t2 = 0; t2 < 2; ++t2)
                oacc[t2][dg] = __builtin_amdgcn_mfma_f32_16x16x32_f16(pf8[t2], v8, oacc[t2][dg], 0, 0, 0);
        }

        // tile boundary: counted wait (newest 2 tiles' loads stay in flight)
        asm volatile("s_waitcnt vmcnt(4)" ::: "memory");
        __builtin_amdgcn_s_barrier();
        asm volatile("" ::: "memory");
    }

    __syncthreads();   // drain all outstanding loads before LDS reuse

    // --- merge key-half partials (O, l) through LDS, two rounds over t.
    // Round size: 4 qg x 64 lanes x 20 f32 = 20 KB (fits in Kt's 32 KB).
    float* mb = (float*)&Kt[0][0];
    #pragma unroll
    for (int t = 0; t < 2; ++t) {
        if (kh == 1) {
            float* p = mb + ((qg * 64 + lane) * 20);
            *(f32x4*)(p +  0) = oacc[t][0];
            *(f32x4*)(p +  4) = oacc[t][1];
            *(f32x4*)(p +  8) = oacc[t][2];
            *(f32x4*)(p + 12) = oacc[t][3];
            *(f32x4*)(p + 16) = lacc[t];
        }
        __syncthreads();
        if (kh == 0) {
            const float* p = mb + ((qg * 64 + lane) * 20);
            f32x4 po[4], pl;
            po[0] = *(const f32x4*)(p +  0);
            po[1] = *(const f32x4*)(p +  4);
            po[2] = *(const f32x4*)(p +  8);
            po[3] = *(const f32x4*)(p + 12);
            pl    = *(const f32x4*)(p + 16);
            #pragma unroll
            for (int r = 0; r < 4; ++r) {
                float linv = 1.0f / (lacc[t][r] + pl[r]);
                int row = qbase + t*16 + quad*4 + r;
                #pragma unroll
                for (int dg = 0; dg < 4; ++dg)
                    ow[((size_t)b * SLEN + row) * EMB + h * DM + dg*16 + c] =
                        (_Float16)((oacc[t][dg][r] + po[dg][r]) * linv);
            }
        }
        __syncthreads();
    }
}

// ---------------------------------------------------------------------------
extern "C" void kernel_launch(void* const* d_in, const int* in_sizes, int n_in,
                              void* d_out, int out_size, void* d_ws, size_t ws_size,
                              hipStream_t stream)
{
    const float* Q  = (const float*)d_in[0];
    const float* K  = (const float*)d_in[1];
    const float* V  = (const float*)d_in[2];
    const float* Wq = (const float*)d_in[3];
    const float* bq = (const float*)d_in[4];
    const float* Wk = (const float*)d_in[5];
    const float* bk = (const float*)d_in[6];
    const float* Wv = (const float*)d_in[7];
    const float* bv = (const float*)d_in[8];
    const float* Wo = (const float*)d_in[9];
    const float* bo = (const float*)d_in[10];
    float* out = (float*)d_out;

    const size_t MN = (size_t)BS * SLEN * NH * DM;   // 4M halves
    const size_t WW = (size_t)EMB * NH * DM;         // 1M halves

    _Float16* base = (_Float16*)d_ws;
    _Float16* Qh   = base;
    _Float16* Kh   = Qh  + MN;
    _Float16* Vh   = Kh  + MN;
    _Float16* WqT  = Vh  + MN;
    _Float16* WkT  = WqT + WW;
    _Float16* WvT  = WkT + WW;
    _Float16* WoT  = WvT + WW;
    _Float16* q_ws = WoT + WW;
    _Float16* k_ws = q_ws + MN;
    _Float16* v_ws = k_ws + MN;
    _Float16* o_ws = v_ws + MN;

    dim3 blk(256);

    prep<<<dim3(2048, 1, 7), blk, 0, stream>>>(Q, K, V, Wq, Wk, Wv, Wo,
                                               Qh, Kh, Vh, WqT, WkT, WvT, WoT);

    gemm_qkv<<<dim3(8, 64, 3), blk, 0, stream>>>(Qh, Kh, Vh, WqT, WkT, WvT,
                                                 bq, bk, bv, q_ws, k_ws, v_ws);

    attn_mfma<<<dim3(SLEN / 128, BS * NH), dim3(512), 0, stream>>>(q_ws, k_ws, v_ws, o_ws);

    gemm_out<<<dim3(8, 64, 1), blk, 0, stream>>>(o_ws, WoT, bo, out);
}